// Round 9
// baseline (294.975 us; speedup 1.0000x reference)
//
#include <hip/hip_runtime.h>
#include <math.h>
#include <stdint.h>
#include <stddef.h>

// ---------------------------------------------------------------------------
// SelfAttention forward, fp32 I/O, bf16 MFMA internally.
// Round 14: attn moved to 32x32 full-rate MFMA. The K=16 PV path (16x16x16
// legacy inst) ran the matrix pipe at HALF rate - PV was 34 us of the 48 us
// MFMA chip-time (model matches MfmaUtil). New: QK = mfma_32x32x16(K,Q) ->
// S^T (q=lane&31, kv=(reg&3)+8*(reg>>2)+4*half); exp2+pack in-reg; ONE
// permlane32_swap per dword-pair builds the full-rate PV A-fragment
// (row=q, k=(lane>>5)*8+i). PV = mfma_32x32x16(P,V). ones-MFMA dropped
// (rowsum = in-reg f32 adds + shfl_xor(32)). Staging/barriers = v8 verbatim.
// GEMM keeps round-12's 2-deep vmcnt(8) pipeline.
// ---------------------------------------------------------------------------

#define SEQ    2048
#define NB     4
#define E_DIM  1024
#define N1     3072
#define M_TOK  8192
#define NHEAD  16
#define DHEAD  64

typedef __attribute__((ext_vector_type(4)))  float    floatx4;
typedef __attribute__((ext_vector_type(16))) float    floatx16;
typedef __attribute__((ext_vector_type(8)))  short    shortx8;
typedef __attribute__((ext_vector_type(4)))  short    shortx4;
typedef __attribute__((ext_vector_type(4)))  unsigned short ushortx4;

#if __has_builtin(__builtin_amdgcn_exp2f)
#define EXP2(x) __builtin_amdgcn_exp2f(x)
#else
#define EXP2(x) __expf((x) * 0.6931471805599453f)
#endif

#define MFMA32(a, b, c) \
    __builtin_amdgcn_mfma_f32_32x32x16_bf16((a), (b), (c), 0, 0, 0)

__device__ __forceinline__ unsigned short f2bf(float f) {
    union { float f; unsigned u; } v; v.f = f;
    unsigned r = (v.u + 0x7FFFu + ((v.u >> 16) & 1u)) >> 16;  // RNE
    return (unsigned short)r;
}
__device__ __forceinline__ unsigned fbits(float f) {
    union { float f; unsigned u; } v; v.f = f; return v.u;
}

__device__ __forceinline__ void gl_lds16(const void* g, void* l) {
    __builtin_amdgcn_global_load_lds(
        (const __attribute__((address_space(1))) unsigned int*)g,
        (__attribute__((address_space(3))) unsigned int*)l, 16, 0, 0);
}

// --------------------------- fp32 -> bf16 convert ---------------------------
__global__ __launch_bounds__(256) void cvt_bf16(
    const float* __restrict__ in, unsigned short* __restrict__ out)
{
    const size_t i = ((size_t)blockIdx.x * 256 + threadIdx.x) * 8;
    float4 a = *(const float4*)(in + i);
    float4 b = *(const float4*)(in + i + 4);
    ushortx4 o0 = { f2bf(a.x), f2bf(a.y), f2bf(a.z), f2bf(a.w) };
    ushortx4 o1 = { f2bf(b.x), f2bf(b.y), f2bf(b.z), f2bf(b.w) };
    *(ushortx4*)(out + i)     = o0;
    *(ushortx4*)(out + i + 4) = o1;
}

// -------------------- fp32 [K][N] -> bf16 transposed [N][K] -----------------
__global__ __launch_bounds__(256) void cvt_transpose(
    const float* __restrict__ W, unsigned short* __restrict__ Wt, int K, int N)
{
    __shared__ unsigned short tile[32][33];
    const int tx = threadIdx.x, ty = threadIdx.y;   // (32, 8)
    const int n0 = blockIdx.x * 32, k0 = blockIdx.y * 32;
#pragma unroll
    for (int r = 0; r < 4; ++r) {
        const int k = ty + r * 8;
        tile[tx][k] = f2bf(W[(size_t)(k0 + k) * N + n0 + tx]);
    }
    __syncthreads();
#pragma unroll
    for (int r = 0; r < 4; ++r) {
        const int n = ty + r * 8;
        Wt[(size_t)(n0 + n) * K + k0 + tx] = tile[n][tx];
    }
}

// --------------------------- bf16 MFMA GEMM --------------------------------
// C[M,N] = A[M,K](bf16) @ Bt[N,K](bf16, pre-transposed) + bias[N](f32).
// BM=BN=128, BK=64, DOUBLE-buffered LDS (64 KB), 2-deep prefetch pipeline
// (vmcnt(8) + raw barriers; no vmcnt(0) drain in the loop). XOR8 swizzle via
// pre-swizzled GLOBAL source chunks + swizzled ds_read.
// FUSE (gemm1 only): Q columns (col%192 < 64) pre-scaled by log2(e)/8;
// V columns (col%192 >= 128) also stored transposed into Vt[bh][d][s].
template <bool OUT_BF16, bool FUSE>
__global__ __launch_bounds__(256) void gemm_bf16(
    const short* __restrict__ A, const short* __restrict__ Bt,
    const float* __restrict__ bias, void* __restrict__ Cout,
    unsigned short* __restrict__ Vt,
    int M, int N, int K)
{
    __shared__ short As[2][128 * 64];
    __shared__ short Bs[2][128 * 64];

    const int t    = threadIdx.x;
    const int lane = t & 63, w = t >> 6;
    const int quad = lane >> 4, l15 = lane & 15;
    const int bm = blockIdx.y * 128, bn = blockIdx.x * 128;
    const int m0w = (w >> 1) * 64, n0w = (w & 1) * 64;

    const int srow   = t >> 3;            // 0..31
    const int schunk = t & 7;             // 16B chunk in 128B row
    const int gch    = schunk ^ (srow & 7);
    const short* Ag = A  + (size_t)(bm + srow) * K + gch * 8;
    const short* Bg = Bt + (size_t)(bn + srow) * K + gch * 8;
    const int sOff = srow * 64 + schunk * 8;   // shorts

    floatx4 acc[4][4];
#pragma unroll
    for (int i = 0; i < 4; ++i)
#pragma unroll
        for (int j = 0; j < 4; ++j) acc[i][j] = (floatx4)0.f;

    const int NK = K >> 6;     // K/64 K-steps

#define GEMM_STAGE(bufi, k0)                                                   \
    {                                                                          \
        _Pragma("unroll")                                                      \
        for (int r = 0; r < 4; ++r) {                                          \
            gl_lds16(Ag + (size_t)(r * 32) * K + (k0), &As[bufi][sOff + r * 32 * 64]); \
            gl_lds16(Bg + (size_t)(r * 32) * K + (k0), &Bs[bufi][sOff + r * 32 * 64]); \
        }                                                                      \
    }

    GEMM_STAGE(0, 0);
    GEMM_STAGE(1, 64);

    for (int kt = 0; kt < NK; ++kt) {
        const int buf = kt & 1;
        if (kt + 1 < NK) asm volatile("s_waitcnt vmcnt(8)" ::: "memory");
        else             asm volatile("s_waitcnt vmcnt(0)" ::: "memory");
        __builtin_amdgcn_sched_barrier(0);
        __builtin_amdgcn_s_barrier();          // publish tile kt
        __builtin_amdgcn_sched_barrier(0);

#pragma unroll
        for (int kk = 0; kk < 2; ++kk) {
            shortx8 af[4], bf[4];
#pragma unroll
            for (int mi = 0; mi < 4; ++mi)
                af[mi] = *(const shortx8*)(&As[buf][(m0w + mi * 16 + l15) * 64
                                           + (((kk * 4 + quad) ^ (l15 & 7)) * 8)]);
#pragma unroll
            for (int ni = 0; ni < 4; ++ni)
                bf[ni] = *(const shortx8*)(&Bs[buf][(n0w + ni * 16 + l15) * 64
                                           + (((kk * 4 + quad) ^ (l15 & 7)) * 8)]);
#pragma unroll
            for (int mi = 0; mi < 4; ++mi)
#pragma unroll
                for (int ni = 0; ni < 4; ++ni)
                    acc[mi][ni] = __builtin_amdgcn_mfma_f32_16x16x32_bf16(
                        af[mi], bf[ni], acc[mi][ni], 0, 0, 0);
        }

        __builtin_amdgcn_sched_barrier(0);
        __builtin_amdgcn_s_barrier();          // buf free
        __builtin_amdgcn_sched_barrier(0);
        if (kt + 2 < NK) GEMM_STAGE(buf, (kt + 2) * 64);
    }
#undef GEMM_STAGE

    float bv[4];
#pragma unroll
    for (int ni = 0; ni < 4; ++ni) bv[ni] = bias[bn + n0w + ni * 16 + l15];

#pragma unroll
    for (int ni = 0; ni < 4; ++ni) {
        const int col   = bn + n0w + ni * 16 + l15;
        const int cm    = col % 192;      // wave-uniform block (no divergence)
        const int vhead = col / 192;
#pragma unroll
        for (int mi = 0; mi < 4; ++mi) {
            const int row0 = bm + m0w + mi * 16 + quad * 4;
            float v[4];
#pragma unroll
            for (int r = 0; r < 4; ++r) v[r] = acc[mi][ni][r] + bv[ni];
            if (OUT_BF16) {
                if (FUSE && cm < DHEAD) {
#pragma unroll
                    for (int r = 0; r < 4; ++r) v[r] *= 0.18033688011112042f;  // log2(e)/8
                }
                unsigned short* H = (unsigned short*)Cout;
#pragma unroll
                for (int r = 0; r < 4; ++r)
                    H[(size_t)(row0 + r) * N + col] = f2bf(v[r]);
                if (FUSE && cm >= 2 * DHEAD) {
                    const int nb = row0 >> 11;       // batch
                    const int s  = row0 & 2047;
                    const int d  = cm - 2 * DHEAD;
                    ushortx4 pk = { f2bf(v[0]), f2bf(v[1]), f2bf(v[2]), f2bf(v[3]) };
                    *(ushortx4*)(Vt + ((size_t)(nb * NHEAD + vhead) * DHEAD + d) * SEQ + s) = pk;
                }
            } else {
                float* C = (float*)Cout;
#pragma unroll
                for (int r = 0; r < 4; ++r)
                    C[(size_t)(row0 + r) * N + col] = v[r];
            }
        }
    }
}

// ------------------------- MFMA flash attention v13 -------------------------
// 256 thr = 4 waves; wave w owns q rows q0+w*32 .. +31, full d=64.
// Per 32-kv subtile: S^T = mfma_32x32x16(K,Q) x4 (d=64). exp2 in f32 regs;
// pack (truncate) to bf16 dwords; permlane32_swap builds the PV A-fragment
// (row=q=lane&31, k=(lane>>5)*8+i) - full-rate PV via mfma_32x32x16(P,V).
// Row sums: f32 adds in-lane (lane&31 = q), cross-half shfl_xor(32) at end.
// K/V staged double-buffered (v8 staging verbatim), one tile in flight.
__global__ __launch_bounds__(256, 4) void attn_mfma(
    const short* __restrict__ h, const short* __restrict__ Vt,
    unsigned short* __restrict__ att)
{
    __shared__ short Ks[2][64 * 64];    // [kv][d], XOR8 16B-chunk swizzle
    __shared__ short Vs[2][64 * 64];    // [d][kv], XOR8 16B-chunk swizzle

    const int t    = threadIdx.x;
    const int lane = t & 63, w = t >> 6;
    const int l31  = lane & 31, hf = lane >> 5;
    const int bh = blockIdx.x, n = bh >> 4, head = bh & 15;
    const int q0w = blockIdx.y * 128 + w * 32;

    const short* hQ  = h + (size_t)n * SEQ * N1 + head * (3 * DHEAD);
    const short* hK  = hQ + DHEAD;
    const short* Vtb = Vt + (size_t)bh * DHEAD * SEQ;

    // staging (v8 verbatim): thread t owns row t>>2, 16B chunks (t&3)*2, +1
    const int srow = t >> 2;
    const int sc0  = (t & 3) * 2;
    const int sk   = srow & 7;
    const short* gK = hK  + (size_t)srow * N1  + sc0 * 8;
    const short* gV = Vtb + (size_t)srow * SEQ + sc0 * 8;
    const int oL0 = srow * 64 + ((sc0    ) ^ sk) * 8;
    const int oL1 = srow * 64 + ((sc0 + 1) ^ sk) * 8;

    // Q B-fragments: col=q=l31, k=d=c*16+hf*8+i  (8 contiguous shorts)
    shortx8 qf[4];
#pragma unroll
    for (int c = 0; c < 4; ++c)
        qf[c] = *(const shortx8*)(hQ + (size_t)(q0w + l31) * N1 + c * 16 + hf * 8);

    floatx16 O0 = (floatx16)0.f;        // d = l31      (cols 0-31)
    floatx16 O1 = (floatx16)0.f;        // d = 32 + l31 (cols 32-63)
    float ls0 = 0.f, ls1 = 0.f;         // row-sum partials, q = l31 (half kv)

    const int NT = SEQ / 64;

    // prologue: tile 0 into buffer 0
    int4 ka = *(const int4*)gK, kb = *(const int4*)(gK + 8);
    int4 va = *(const int4*)gV, vb = *(const int4*)(gV + 8);
    *(int4*)(&Ks[0][oL0]) = ka; *(int4*)(&Ks[0][oL1]) = kb;
    *(int4*)(&Vs[0][oL0]) = va; *(int4*)(&Vs[0][oL1]) = vb;
    gK += (size_t)64 * N1; gV += 64;

    for (int it = 0; it < NT; ++it) {
        const int buf = it & 1;
        __syncthreads();                // buf ready

        const bool more = (it + 1 < NT);
        if (more) {                     // issue next-tile global loads early
            ka = *(const int4*)gK; kb = *(const int4*)(gK + 8);
            va = *(const int4*)gV; vb = *(const int4*)(gV + 8);
            gK += (size_t)64 * N1; gV += 64;
        }

        const short* Kb = &Ks[buf][0];
        const short* Vb = &Vs[buf][0];

        __builtin_amdgcn_s_setprio(1);
#pragma unroll
        for (int sub = 0; sub < 2; ++sub) {
            // K A-fragments: row = kv = sub*32 + l31, k = d = c*16 + hf*8 + i
            const int krow = sub * 32 + l31;
            const short* kbase = Kb + krow * 64;
            shortx8 kf[4];
#pragma unroll
            for (int c = 0; c < 4; ++c)
                kf[c] = *(const shortx8*)(kbase + (((c * 2 + hf) ^ (krow & 7)) * 8));

            // S^T (32kv x 32q): contraction over d = 64
            floatx16 s = (floatx16)0.f;
#pragma unroll
            for (int c = 0; c < 4; ++c)
                s = MFMA32(kf[c], qf[c], s);

            // exp2 + row-sum partials (lane's 16 kv values for q = l31)
            float p[16];
#pragma unroll
            for (int i = 0; i < 8; ++i)  { p[i] = EXP2(s[i]); ls0 += p[i]; }
#pragma unroll
            for (int i = 8; i < 16; ++i) { p[i] = EXP2(s[i]); ls1 += p[i]; }

            // PV per 16-kv step: pack + permlane32_swap -> A-frag, 2 d-halves
#pragma unroll
            for (int ks = 0; ks < 2; ++ks) {
                const int b = ks * 8;
                const unsigned A0 = __builtin_amdgcn_perm(fbits(p[b + 1]), fbits(p[b + 0]), 0x07060302u);
                const unsigned A1 = __builtin_amdgcn_perm(fbits(p[b + 3]), fbits(p[b + 2]), 0x07060302u);
                const unsigned B0 = __builtin_amdgcn_perm(fbits(p[b + 5]), fbits(p[b + 4]), 0x07060302u);
                const unsigned B1 = __builtin_amdgcn_perm(fbits(p[b + 7]), fbits(p[b + 6]), 0x07060302u);
                const auto r0 = __builtin_amdgcn_permlane32_swap(A0, B0, false, false);
                const auto r1 = __builtin_amdgcn_permlane32_swap(A1, B1, false, false);
                union { unsigned u[4]; shortx8 v; } pc;
                pc.u[0] = r0[0]; pc.u[1] = r1[0]; pc.u[2] = r0[1]; pc.u[3] = r1[1];

                const int vch = sub * 4 + ks * 2 + hf;   // 16B kv-chunk index
                const int vr0 = l31;                     // d rows 0-31
                const int vr1 = 32 + l31;                // d rows 32-63
                shortx8 vf0 = *(const shortx8*)(Vb + vr0 * 64 + ((vch ^ (vr0 & 7)) * 8));
                shortx8 vf1 = *(const shortx8*)(Vb + vr1 * 64 + ((vch ^ (vr1 & 7)) * 8));
                O0 = MFMA32(pc.v, vf0, O0);
                O1 = MFMA32(pc.v, vf1, O1);
            }
        }
        __builtin_amdgcn_s_setprio(0);

        if (more) {                     // stage next tile into other buffer
            short* Kn = &Ks[buf ^ 1][0];
            short* Vn = &Vs[buf ^ 1][0];
            *(int4*)(Kn + oL0) = ka; *(int4*)(Kn + oL1) = kb;
            *(int4*)(Vn + oL0) = va; *(int4*)(Vn + oL1) = vb;
        }
    }

    // total row sum for q = l31: own half + partner half
    float tot = ls0 + ls1;
    tot += __shfl_xor(tot, 32);

    // epilogue: O row = q = (reg&3) + 8*(reg>>2) + 4*hf, col d = l31 (+32)
    const size_t obase = ((size_t)n * SEQ + q0w) * E_DIM + head * DHEAD;
#pragma unroll
    for (int reg = 0; reg < 16; ++reg) {
        const int qr = (reg & 3) + 8 * (reg >> 2) + 4 * hf;
        const float inv = 1.f / __shfl(tot, qr);
        const size_t row = obase + (size_t)qr * E_DIM;
        att[row + l31]      = f2bf(O0[reg] * inv);
        att[row + 32 + l31] = f2bf(O1[reg] * inv);
    }
}

// ------------------------------- launch ------------------------------------
extern "C" void kernel_launch(void* const* d_in, const int* in_sizes, int n_in,
                              void* d_out, int out_size, void* d_ws, size_t ws_size,
                              hipStream_t stream)
{
    const float* x  = (const float*)d_in[0];
    const float* W1 = (const float*)d_in[1];
    const float* b1 = (const float*)d_in[2];
    const float* W2 = (const float*)d_in[3];
    const float* b2 = (const float*)d_in[4];
    float* out = (float*)d_out;

    char* ws = (char*)d_ws;
    unsigned short* x_bf  = (unsigned short*)(ws);                    // 16 MB
    unsigned short* W1t   = (unsigned short*)(ws + (16u << 20));      //  6 MB
    unsigned short* W2t   = (unsigned short*)(ws + (22u << 20));      //  2 MB
    unsigned short* h_bf  = (unsigned short*)(ws + (24u << 20));      // 48 MB
    unsigned short* attb  = (unsigned short*)(ws + (72u << 20));      // 16 MB
    unsigned short* Vtw   = (unsigned short*)(ws + (88u << 20));      // 16 MB

    cvt_bf16<<<dim3((M_TOK * E_DIM) / (256 * 8)), 256, 0, stream>>>(x, x_bf);
    cvt_transpose<<<dim3(N1 / 32, E_DIM / 32), dim3(32, 8), 0, stream>>>(W1, W1t, E_DIM, N1);
    cvt_transpose<<<dim3(E_DIM / 32, E_DIM / 32), dim3(32, 8), 0, stream>>>(W2, W2t, E_DIM, E_DIM);

    // h = x@W1+b1 (bf16; Q cols pre-scaled log2(e)/8; V cols also -> Vt transposed)
    gemm_bf16<true, true><<<dim3(N1 / 128, M_TOK / 128), 256, 0, stream>>>(
        (const short*)x_bf, (const short*)W1t, b1, h_bf, Vtw, M_TOK, N1, E_DIM);

    attn_mfma<<<dim3(NB * NHEAD, SEQ / 128), 256, 0, stream>>>(
        (const short*)h_bf, (const short*)Vtw, attb);

    gemm_bf16<false, false><<<dim3(E_DIM / 128, M_TOK / 128), 256, 0, stream>>>(
        (const short*)attb, (const short*)W2t, b2, out, nullptr, M_TOK, E_DIM, E_DIM);
}

// Round 10
// 284.115 us; speedup vs baseline: 1.0382x; 1.0382x over previous
//
#include <hip/hip_runtime.h>
#include <math.h>
#include <stdint.h>
#include <stddef.h>

// ---------------------------------------------------------------------------
// SelfAttention forward, fp32 I/O, bf16 MFMA internally.
// Round 15: attn reverted to v8 verbatim (90 us; every structural variant
// r3/r4/r6/r8/r9 regressed to 92-120). GEMM re-tiled to 256x128 with 512
// threads / 8 waves, SAME 2-barrier + counted-vmcnt(6) pipeline (parameter
// change only): halves barriers-per-FLOP and A-panel fetch; grids become
// exact (768=3.0/CU, 256=1.0/CU). gemm1 no longer stores V cols into h_bf
// (attn reads V via Vt only) - saves 16 MB writes.
// ---------------------------------------------------------------------------

#define SEQ    2048
#define NB     4
#define E_DIM  1024
#define N1     3072
#define M_TOK  8192
#define NHEAD  16
#define DHEAD  64

typedef __attribute__((ext_vector_type(4))) float    floatx4;
typedef __attribute__((ext_vector_type(8))) short    shortx8;
typedef __attribute__((ext_vector_type(4))) short    shortx4;
typedef __attribute__((ext_vector_type(4))) unsigned short ushortx4;

#if __has_builtin(__builtin_amdgcn_exp2f)
#define EXP2(x) __builtin_amdgcn_exp2f(x)
#else
#define EXP2(x) __expf((x) * 0.6931471805599453f)
#endif

// K=16 bf16 MFMA: A,B = 4x bf16 (2 VGPRs), C/D = 4x f32. A layout
// (row=lane&15, k=quad*4+i) is the exact transpose of the 16x16 C/D layout.
#define MFMA_K16(a, b, c) \
    __builtin_amdgcn_mfma_f32_16x16x16bf16_1k((a), (b), (c), 0, 0, 0)

__device__ __forceinline__ unsigned short f2bf(float f) {
    union { float f; unsigned u; } v; v.f = f;
    unsigned r = (v.u + 0x7FFFu + ((v.u >> 16) & 1u)) >> 16;  // RNE
    return (unsigned short)r;
}
__device__ __forceinline__ unsigned fbits(float f) {
    union { float f; unsigned u; } v; v.f = f; return v.u;
}

__device__ __forceinline__ void gl_lds16(const void* g, void* l) {
    __builtin_amdgcn_global_load_lds(
        (const __attribute__((address_space(1))) unsigned int*)g,
        (__attribute__((address_space(3))) unsigned int*)l, 16, 0, 0);
}

// --------------------------- fp32 -> bf16 convert ---------------------------
__global__ __launch_bounds__(256) void cvt_bf16(
    const float* __restrict__ in, unsigned short* __restrict__ out)
{
    const size_t i = ((size_t)blockIdx.x * 256 + threadIdx.x) * 8;
    float4 a = *(const float4*)(in + i);
    float4 b = *(const float4*)(in + i + 4);
    ushortx4 o0 = { f2bf(a.x), f2bf(a.y), f2bf(a.z), f2bf(a.w) };
    ushortx4 o1 = { f2bf(b.x), f2bf(b.y), f2bf(b.z), f2bf(b.w) };
    *(ushortx4*)(out + i)     = o0;
    *(ushortx4*)(out + i + 4) = o1;
}

// -------------------- fp32 [K][N] -> bf16 transposed [N][K] -----------------
__global__ __launch_bounds__(256) void cvt_transpose(
    const float* __restrict__ W, unsigned short* __restrict__ Wt, int K, int N)
{
    __shared__ unsigned short tile[32][33];
    const int tx = threadIdx.x, ty = threadIdx.y;   // (32, 8)
    const int n0 = blockIdx.x * 32, k0 = blockIdx.y * 32;
#pragma unroll
    for (int r = 0; r < 4; ++r) {
        const int k = ty + r * 8;
        tile[tx][k] = f2bf(W[(size_t)(k0 + k) * N + n0 + tx]);
    }
    __syncthreads();
#pragma unroll
    for (int r = 0; r < 4; ++r) {
        const int n = ty + r * 8;
        Wt[(size_t)(n0 + n) * K + k0 + tx] = tile[n][tx];
    }
}

// --------------------------- bf16 MFMA GEMM --------------------------------
// C[M,N] = A[M,K](bf16) @ Bt[N,K](bf16, pre-transposed) + bias[N](f32).
// BM=256, BN=128, BK=64, 512 thr / 8 waves (wave = 64x64 out), double-
// buffered 96 KB LDS, 2-deep prefetch pipeline:
//   iter t: vmcnt(6) [tile t landed; t+1 in flight] -> s_barrier (publish)
//           -> ds_read frags + 32 MFMA/wave on buf[t] -> s_barrier (free)
//           -> 6x global_load_lds tile t+2 into buf[t]
// XOR8 swizzle via pre-swizzled GLOBAL source chunks (gl_lds dest linear)
// + swizzled ds_read. FUSE (gemm1): Q cols (col%192<64) pre-scaled by
// log2(e)/8; V cols (col%192>=128) stored ONLY into Vt[bh][d][s] transposed.
template <bool OUT_BF16, bool FUSE>
__global__ __launch_bounds__(512) void gemm_bf16(
    const short* __restrict__ A, const short* __restrict__ Bt,
    const float* __restrict__ bias, void* __restrict__ Cout,
    unsigned short* __restrict__ Vt,
    int M, int N, int K)
{
    __shared__ short As[2][256 * 64];   // 64 KB
    __shared__ short Bs[2][128 * 64];   // 32 KB

    const int t    = threadIdx.x;
    const int lane = t & 63, w = t >> 6;           // 8 waves
    const int quad = lane >> 4, l15 = lane & 15;
    const int bm = blockIdx.y * 256, bn = blockIdx.x * 128;
    const int m0w = (w >> 1) * 64, n0w = (w & 1) * 64;

    // staging: thread t owns rows t>>3 (+64 steps), 16B chunk t&7.
    // Global chunk pre-swizzled by row&7 (invariant under +64); LDS dest
    // linear: byte t*16 (+8 KB per row-step) = wave-uniform + lane*16.
    const int srow   = t >> 3;            // 0..63
    const int schunk = t & 7;
    const int gch    = schunk ^ (srow & 7);
    const short* Ag = A  + (size_t)(bm + srow) * K + gch * 8;
    const short* Bg = Bt + (size_t)(bn + srow) * K + gch * 8;
    const int sOff = t * 8;               // shorts

    floatx4 acc[4][4];
#pragma unroll
    for (int i = 0; i < 4; ++i)
#pragma unroll
        for (int j = 0; j < 4; ++j) acc[i][j] = (floatx4)0.f;

    const int NK = K >> 6;     // K/64 K-steps

#define GEMM_STAGE(bufi, k0)                                                   \
    {                                                                          \
        _Pragma("unroll")                                                      \
        for (int r = 0; r < 4; ++r)                                            \
            gl_lds16(Ag + (size_t)(r * 64) * K + (k0), &As[bufi][sOff + r * 64 * 64]); \
        _Pragma("unroll")                                                      \
        for (int r = 0; r < 2; ++r)                                            \
            gl_lds16(Bg + (size_t)(r * 64) * K + (k0), &Bs[bufi][sOff + r * 64 * 64]); \
    }

    // prologue: tiles 0 and 1 in flight (12 outstanding loads/thread)
    GEMM_STAGE(0, 0);
    GEMM_STAGE(1, 64);

    for (int kt = 0; kt < NK; ++kt) {
        const int buf = kt & 1;
        // wait for tile kt (6 newest = tile kt+1 may stay in flight)
        if (kt + 1 < NK) asm volatile("s_waitcnt vmcnt(6)" ::: "memory");
        else             asm volatile("s_waitcnt vmcnt(0)" ::: "memory");
        __builtin_amdgcn_sched_barrier(0);
        __builtin_amdgcn_s_barrier();          // publish tile kt to all waves
        __builtin_amdgcn_sched_barrier(0);

#pragma unroll
        for (int kk = 0; kk < 2; ++kk) {
            shortx8 af[4], bf[4];
#pragma unroll
            for (int mi = 0; mi < 4; ++mi)
                af[mi] = *(const shortx8*)(&As[buf][(m0w + mi * 16 + l15) * 64
                                           + (((kk * 4 + quad) ^ (l15 & 7)) * 8)]);
#pragma unroll
            for (int ni = 0; ni < 4; ++ni)
                bf[ni] = *(const shortx8*)(&Bs[buf][(n0w + ni * 16 + l15) * 64
                                           + (((kk * 4 + quad) ^ (l15 & 7)) * 8)]);
#pragma unroll
            for (int mi = 0; mi < 4; ++mi)
#pragma unroll
                for (int ni = 0; ni < 4; ++ni)
                    acc[mi][ni] = __builtin_amdgcn_mfma_f32_16x16x32_bf16(
                        af[mi], bf[ni], acc[mi][ni], 0, 0, 0);
        }

        __builtin_amdgcn_sched_barrier(0);
        __builtin_amdgcn_s_barrier();          // all waves done reading buf
        __builtin_amdgcn_sched_barrier(0);
        if (kt + 2 < NK) GEMM_STAGE(buf, (kt + 2) * 64);
    }
#undef GEMM_STAGE

    float bv[4];
#pragma unroll
    for (int ni = 0; ni < 4; ++ni) bv[ni] = bias[bn + n0w + ni * 16 + l15];

#pragma unroll
    for (int ni = 0; ni < 4; ++ni) {
        const int col   = bn + n0w + ni * 16 + l15;
        const int cm    = col % 192;      // wave-uniform block (no divergence)
        const int vhead = col / 192;
#pragma unroll
        for (int mi = 0; mi < 4; ++mi) {
            const int row0 = bm + m0w + mi * 16 + quad * 4;
            float v[4];
#pragma unroll
            for (int r = 0; r < 4; ++r) v[r] = acc[mi][ni][r] + bv[ni];
            if (OUT_BF16) {
                if (FUSE && cm >= 2 * DHEAD) {
                    // V columns: ONLY the transposed Vt store (h_bf V cols
                    // are never read by attn)
                    const int nb = row0 >> 11;       // batch
                    const int s  = row0 & 2047;
                    const int d  = cm - 2 * DHEAD;
                    ushortx4 pk = { f2bf(v[0]), f2bf(v[1]), f2bf(v[2]), f2bf(v[3]) };
                    *(ushortx4*)(Vt + ((size_t)(nb * NHEAD + vhead) * DHEAD + d) * SEQ + s) = pk;
                } else {
                    if (FUSE && cm < DHEAD) {
#pragma unroll
                        for (int r = 0; r < 4; ++r) v[r] *= 0.18033688011112042f;  // log2(e)/8
                    }
                    unsigned short* H = (unsigned short*)Cout;
#pragma unroll
                    for (int r = 0; r < 4; ++r)
                        H[(size_t)(row0 + r) * N + col] = f2bf(v[r]);
                }
            } else {
                float* C = (float*)Cout;
#pragma unroll
                for (int r = 0; r < 4; ++r)
                    C[(size_t)(row0 + r) * N + col] = v[r];
            }
        }
    }
}

// ------------------------- MFMA flash attention v8 --------------------------
// (verbatim round-2/7 version: 90.0-90.4 us measured; all variants regressed)
// 256 thr = 4 independent waves; wave w owns q rows q0+w*32 .. +31, full d=64.
// Per 16-kv slab: S^T = mfma16x16x32(K,Q) -> exp2 -> pack bf16 in-lane; the
// packed regs ARE the A-fragment of mfma_16x16x16bf16_1k (layout duality), so
// PV needs no LDS P and no cross-lane. Row sums: extra K=16 MFMA vs ones.
// K/V staged in double-buffered LDS; ONE __syncthreads per 64-kv tile.
__global__ __launch_bounds__(256, 4) void attn_mfma(
    const short* __restrict__ h, const short* __restrict__ Vt,
    unsigned short* __restrict__ att)
{
    __shared__ short Ks[2][64 * 64];    // [kv][d], XOR8 16B-chunk swizzle
    __shared__ short Vs[2][64 * 64];    // [d][kv], XOR8 16B-chunk swizzle

    const int t    = threadIdx.x;
    const int lane = t & 63, w = t >> 6;
    const int quad = lane >> 4, l15 = lane & 15;
    const int r7   = l15 & 7;
    const int bh = blockIdx.x, n = bh >> 4, head = bh & 15;
    const int q0 = blockIdx.y * 128 + w * 32;

    const short* hQ  = h + (size_t)n * SEQ * N1 + head * (3 * DHEAD);
    const short* hK  = hQ + DHEAD;
    const short* Vtb = Vt + (size_t)bh * DHEAD * SEQ;

    // staging: thread t owns row t>>2, 16B chunks (t&3)*2 and +1 (K and V)
    const int srow = t >> 2;
    const int sc0  = (t & 3) * 2;
    const int sk   = srow & 7;
    const short* gK = hK  + (size_t)srow * N1  + sc0 * 8;
    const short* gV = Vtb + (size_t)srow * SEQ + sc0 * 8;
    const int oL0 = srow * 64 + ((sc0    ) ^ sk) * 8;
    const int oL1 = srow * 64 + ((sc0 + 1) ^ sk) * 8;

    // Q fragments: 32 rows per wave, hoisted once
    shortx8 qf[2][2];
#pragma unroll
    for (int qt = 0; qt < 2; ++qt)
#pragma unroll
        for (int kt = 0; kt < 2; ++kt)
            qf[qt][kt] = *(const shortx8*)(hQ + (size_t)(q0 + qt * 16 + l15) * N1
                                           + kt * 32 + quad * 8);

    floatx4 O[2][4];                    // q-tile x d-tile, full d per wave
    floatx4 Osum[2];                    // row sums via ones-MFMA
#pragma unroll
    for (int qt = 0; qt < 2; ++qt) {
        Osum[qt] = (floatx4)0.f;
#pragma unroll
        for (int dt = 0; dt < 4; ++dt) O[qt][dt] = (floatx4)0.f;
    }

    const shortx4 ones = { (short)0x3F80, (short)0x3F80, (short)0x3F80, (short)0x3F80 };

    const int NT = SEQ / 64;

    // prologue: tile 0 into buffer 0
    int4 ka = *(const int4*)gK, kb = *(const int4*)(gK + 8);
    int4 va = *(const int4*)gV, vb = *(const int4*)(gV + 8);
    *(int4*)(&Ks[0][oL0]) = ka; *(int4*)(&Ks[0][oL1]) = kb;
    *(int4*)(&Vs[0][oL0]) = va; *(int4*)(&Vs[0][oL1]) = vb;
    gK += (size_t)64 * N1; gV += 64;

    for (int it = 0; it < NT; ++it) {
        const int buf = it & 1;
        __syncthreads();                // buf ready (written prev iter/prologue)

        const bool more = (it + 1 < NT);
        if (more) {                     // issue next-tile global loads early
            ka = *(const int4*)gK; kb = *(const int4*)(gK + 8);
            va = *(const int4*)gV; vb = *(const int4*)(gV + 8);
            gK += (size_t)64 * N1; gV += 64;
        }

        const short* Kb = &Ks[buf][0];
        const short* Vb = &Vs[buf][0];

#pragma unroll
        for (int sl = 0; sl < 4; ++sl) {
            // K fragments (b128, swizzled, 8-lane/chunk = b128 floor)
            const short* krow = Kb + (sl * 16 + l15) * 64;
            shortx8 kf0 = *(const shortx8*)(krow + ((quad ^ r7) * 8));
            shortx8 kf1 = *(const shortx8*)(krow + (((quad ^ 4) ^ r7) * 8));
            // V fragments for K=16 PV: B[k=kv=quad*4+i][col=d=l15] contiguous 8B
            shortx4 vf[4];
#pragma unroll
            for (int dt = 0; dt < 4; ++dt)
                vf[dt] = *(const shortx4*)(Vb + (dt * 16 + l15) * 64
                                           + (((sl * 4 + quad) ^ (r7 << 1)) << 2));

            // S^T then exp2 then pack: registers become PV A-fragments
            shortx4 pa[2];
#pragma unroll
            for (int qt = 0; qt < 2; ++qt) {
                floatx4 s = __builtin_amdgcn_mfma_f32_16x16x32_bf16(
                    kf0, qf[qt][0], (floatx4)0.f, 0, 0, 0);
                s = __builtin_amdgcn_mfma_f32_16x16x32_bf16(
                    kf1, qf[qt][1], s, 0, 0, 0);
                const float p0 = EXP2(s[0]);
                const float p1 = EXP2(s[1]);
                const float p2 = EXP2(s[2]);
                const float p3 = EXP2(s[3]);
                union { uint2 u; shortx4 v; } cv;
                cv.u.x = __builtin_amdgcn_perm(fbits(p1), fbits(p0), 0x07060302u);
                cv.u.y = __builtin_amdgcn_perm(fbits(p3), fbits(p2), 0x07060302u);
                pa[qt] = cv.v;
            }

            // O += P @ V ; Osum += P @ 1 (row sums land in (quad*4+r) layout)
#pragma unroll
            for (int qt = 0; qt < 2; ++qt) {
                Osum[qt] = MFMA_K16(pa[qt], ones, Osum[qt]);
#pragma unroll
                for (int dt = 0; dt < 4; ++dt)
                    O[qt][dt] = MFMA_K16(pa[qt], vf[dt], O[qt][dt]);
            }
        }

        if (more) {                     // stage next tile into other buffer
            short* Kn = &Ks[buf ^ 1][0];
            short* Vn = &Vs[buf ^ 1][0];
            *(int4*)(Kn + oL0) = ka; *(int4*)(Kn + oL1) = kb;
            *(int4*)(Vn + oL0) = va; *(int4*)(Vn + oL1) = vb;
        }
    }

    // epilogue: normalize and store (no cross-lane needed; Osum layout matches)
    const size_t obase = ((size_t)n * SEQ + q0) * E_DIM + head * DHEAD;
#pragma unroll
    for (int qt = 0; qt < 2; ++qt)
#pragma unroll
        for (int r = 0; r < 4; ++r) {
            const float inv = 1.f / Osum[qt][r];
            const size_t row = obase + (size_t)(qt * 16 + quad * 4 + r) * E_DIM;
#pragma unroll
            for (int dt = 0; dt < 4; ++dt)
                att[row + dt * 16 + l15] = f2bf(O[qt][dt][r] * inv);
        }
}

// ------------------------------- launch ------------------------------------
extern "C" void kernel_launch(void* const* d_in, const int* in_sizes, int n_in,
                              void* d_out, int out_size, void* d_ws, size_t ws_size,
                              hipStream_t stream)
{
    const float* x  = (const float*)d_in[0];
    const float* W1 = (const float*)d_in[1];
    const float* b1 = (const float*)d_in[2];
    const float* W2 = (const float*)d_in[3];
    const float* b2 = (const float*)d_in[4];
    float* out = (float*)d_out;

    char* ws = (char*)d_ws;
    unsigned short* x_bf  = (unsigned short*)(ws);                    // 16 MB
    unsigned short* W1t   = (unsigned short*)(ws + (16u << 20));      //  6 MB
    unsigned short* W2t   = (unsigned short*)(ws + (22u << 20));      //  2 MB
    unsigned short* h_bf  = (unsigned short*)(ws + (24u << 20));      // 48 MB
    unsigned short* attb  = (unsigned short*)(ws + (72u << 20));      // 16 MB
    unsigned short* Vtw   = (unsigned short*)(ws + (88u << 20));      // 16 MB

    cvt_bf16<<<dim3((M_TOK * E_DIM) / (256 * 8)), 256, 0, stream>>>(x, x_bf);
    cvt_transpose<<<dim3(N1 / 32, E_DIM / 32), dim3(32, 8), 0, stream>>>(W1, W1t, E_DIM, N1);
    cvt_transpose<<<dim3(E_DIM / 32, E_DIM / 32), dim3(32, 8), 0, stream>>>(W2, W2t, E_DIM, E_DIM);

    // h = x@W1+b1 (bf16; Q cols pre-scaled log2(e)/8; V cols -> Vt only)
    gemm_bf16<true, true><<<dim3(N1 / 128, M_TOK / 256), 512, 0, stream>>>(
        (const short*)x_bf, (const short*)W1t, b1, h_bf, Vtw, M_TOK, N1, E_DIM);

    attn_mfma<<<dim3(NB * NHEAD, SEQ / 128), 256, 0, stream>>>(
        (const short*)h_bf, (const short*)Vtw, attb);

    gemm_bf16<false, false><<<dim3(E_DIM / 128, M_TOK / 256), 512, 0, stream>>>(
        (const short*)attb, (const short*)W2t, b2, out, nullptr, M_TOK, E_DIM, E_DIM);
}

// Round 11
// 271.163 us; speedup vs baseline: 1.0878x; 1.0478x over previous
//
#include <hip/hip_runtime.h>
#include <math.h>
#include <stdint.h>
#include <stddef.h>

// ---------------------------------------------------------------------------
// SelfAttention forward, fp32 I/O, bf16 MFMA internally.
// Round 16: revert GEMM to the round-12-verified 128x128 / 256-thr / BK=64
// double-buffered vmcnt(8) pipeline (r15's 256-tile cut residency to 1
// block/CU and lost 20 us). Keep r15's V-column epilogue elision. NEW: T1
// bijective XCD-chunk swizzle on both gemm grids (1536%8==0, 512%8==0) so
// blocks sharing an A-row panel land on the same XCD L2. attn = v8 verbatim.
// ---------------------------------------------------------------------------

#define SEQ    2048
#define NB     4
#define E_DIM  1024
#define N1     3072
#define M_TOK  8192
#define NHEAD  16
#define DHEAD  64

typedef __attribute__((ext_vector_type(4))) float    floatx4;
typedef __attribute__((ext_vector_type(8))) short    shortx8;
typedef __attribute__((ext_vector_type(4))) short    shortx4;
typedef __attribute__((ext_vector_type(4))) unsigned short ushortx4;

#if __has_builtin(__builtin_amdgcn_exp2f)
#define EXP2(x) __builtin_amdgcn_exp2f(x)
#else
#define EXP2(x) __expf((x) * 0.6931471805599453f)
#endif

// K=16 bf16 MFMA: A,B = 4x bf16 (2 VGPRs), C/D = 4x f32. A layout
// (row=lane&15, k=quad*4+i) is the exact transpose of the 16x16 C/D layout.
#define MFMA_K16(a, b, c) \
    __builtin_amdgcn_mfma_f32_16x16x16bf16_1k((a), (b), (c), 0, 0, 0)

__device__ __forceinline__ unsigned short f2bf(float f) {
    union { float f; unsigned u; } v; v.f = f;
    unsigned r = (v.u + 0x7FFFu + ((v.u >> 16) & 1u)) >> 16;  // RNE
    return (unsigned short)r;
}
__device__ __forceinline__ unsigned fbits(float f) {
    union { float f; unsigned u; } v; v.f = f; return v.u;
}

__device__ __forceinline__ void gl_lds16(const void* g, void* l) {
    __builtin_amdgcn_global_load_lds(
        (const __attribute__((address_space(1))) unsigned int*)g,
        (__attribute__((address_space(3))) unsigned int*)l, 16, 0, 0);
}

// --------------------------- fp32 -> bf16 convert ---------------------------
__global__ __launch_bounds__(256) void cvt_bf16(
    const float* __restrict__ in, unsigned short* __restrict__ out)
{
    const size_t i = ((size_t)blockIdx.x * 256 + threadIdx.x) * 8;
    float4 a = *(const float4*)(in + i);
    float4 b = *(const float4*)(in + i + 4);
    ushortx4 o0 = { f2bf(a.x), f2bf(a.y), f2bf(a.z), f2bf(a.w) };
    ushortx4 o1 = { f2bf(b.x), f2bf(b.y), f2bf(b.z), f2bf(b.w) };
    *(ushortx4*)(out + i)     = o0;
    *(ushortx4*)(out + i + 4) = o1;
}

// -------------------- fp32 [K][N] -> bf16 transposed [N][K] -----------------
__global__ __launch_bounds__(256) void cvt_transpose(
    const float* __restrict__ W, unsigned short* __restrict__ Wt, int K, int N)
{
    __shared__ unsigned short tile[32][33];
    const int tx = threadIdx.x, ty = threadIdx.y;   // (32, 8)
    const int n0 = blockIdx.x * 32, k0 = blockIdx.y * 32;
#pragma unroll
    for (int r = 0; r < 4; ++r) {
        const int k = ty + r * 8;
        tile[tx][k] = f2bf(W[(size_t)(k0 + k) * N + n0 + tx]);
    }
    __syncthreads();
#pragma unroll
    for (int r = 0; r < 4; ++r) {
        const int n = ty + r * 8;
        Wt[(size_t)(n0 + n) * K + k0 + tx] = tile[n][tx];
    }
}

// --------------------------- bf16 MFMA GEMM --------------------------------
// C[M,N] = A[M,K](bf16) @ Bt[N,K](bf16, pre-transposed) + bias[N](f32).
// BM=BN=128, BK=64, DOUBLE-buffered LDS (64 KB, 2 blocks/CU), 2-deep
// prefetch pipeline (vmcnt(8) + raw barriers; no vmcnt(0) drain in-loop).
// XOR8 swizzle via pre-swizzled GLOBAL source chunks + swizzled ds_read.
// T1: bijective XCD-chunk swizzle of the linear block id (requires
// nwg % 8 == 0; both launches satisfy this) for A-panel L2 locality.
// FUSE (gemm1): Q cols (col%192<64) pre-scaled by log2(e)/8; V cols
// (col%192>=128) stored ONLY into Vt[bh][d][s] (h_bf V cols never read).
template <bool OUT_BF16, bool FUSE>
__global__ __launch_bounds__(256) void gemm_bf16(
    const short* __restrict__ A, const short* __restrict__ Bt,
    const float* __restrict__ bias, void* __restrict__ Cout,
    unsigned short* __restrict__ Vt,
    int M, int N, int K)
{
    __shared__ short As[2][128 * 64];
    __shared__ short Bs[2][128 * 64];

    const int t    = threadIdx.x;
    const int lane = t & 63, w = t >> 6;
    const int quad = lane >> 4, l15 = lane & 15;

    // T1 XCD swizzle: hardware XCD = lid % 8; give each XCD a contiguous
    // chunk of tiles (consecutive tiles share the A row-panel, x-fastest).
    const int nwg = gridDim.x * gridDim.y;
    int lid = blockIdx.y * gridDim.x + blockIdx.x;
    lid = (lid & 7) * (nwg >> 3) + (lid >> 3);
    const int bxs = lid % gridDim.x, bys = lid / gridDim.x;
    const int bm = bys * 128, bn = bxs * 128;
    const int m0w = (w >> 1) * 64, n0w = (w & 1) * 64;

    // staging: thread t owns row t>>3 (+32 per round), 16B chunk t&7.
    // Global chunk pre-swizzled by row&7; LDS dest linear (lane*16B per wave).
    const int srow   = t >> 3;            // 0..31
    const int schunk = t & 7;             // 16B chunk in 128B row
    const int gch    = schunk ^ (srow & 7);
    const short* Ag = A  + (size_t)(bm + srow) * K + gch * 8;
    const short* Bg = Bt + (size_t)(bn + srow) * K + gch * 8;
    const int sOff = srow * 64 + schunk * 8;   // shorts

    floatx4 acc[4][4];
#pragma unroll
    for (int i = 0; i < 4; ++i)
#pragma unroll
        for (int j = 0; j < 4; ++j) acc[i][j] = (floatx4)0.f;

    const int NK = K >> 6;     // K/64 K-steps

#define GEMM_STAGE(bufi, k0)                                                   \
    {                                                                          \
        _Pragma("unroll")                                                      \
        for (int r = 0; r < 4; ++r) {                                          \
            gl_lds16(Ag + (size_t)(r * 32) * K + (k0), &As[bufi][sOff + r * 32 * 64]); \
            gl_lds16(Bg + (size_t)(r * 32) * K + (k0), &Bs[bufi][sOff + r * 32 * 64]); \
        }                                                                      \
    }

    // prologue: tiles 0 and 1 in flight (16 outstanding loads)
    GEMM_STAGE(0, 0);
    GEMM_STAGE(1, 64);

    for (int kt = 0; kt < NK; ++kt) {
        const int buf = kt & 1;
        // wait for tile kt (8 newest = tile kt+1 may stay in flight)
        if (kt + 1 < NK) asm volatile("s_waitcnt vmcnt(8)" ::: "memory");
        else             asm volatile("s_waitcnt vmcnt(0)" ::: "memory");
        __builtin_amdgcn_sched_barrier(0);
        __builtin_amdgcn_s_barrier();          // publish tile kt to all waves
        __builtin_amdgcn_sched_barrier(0);

#pragma unroll
        for (int kk = 0; kk < 2; ++kk) {
            shortx8 af[4], bf[4];
#pragma unroll
            for (int mi = 0; mi < 4; ++mi)
                af[mi] = *(const shortx8*)(&As[buf][(m0w + mi * 16 + l15) * 64
                                           + (((kk * 4 + quad) ^ (l15 & 7)) * 8)]);
#pragma unroll
            for (int ni = 0; ni < 4; ++ni)
                bf[ni] = *(const shortx8*)(&Bs[buf][(n0w + ni * 16 + l15) * 64
                                           + (((kk * 4 + quad) ^ (l15 & 7)) * 8)]);
#pragma unroll
            for (int mi = 0; mi < 4; ++mi)
#pragma unroll
                for (int ni = 0; ni < 4; ++ni)
                    acc[mi][ni] = __builtin_amdgcn_mfma_f32_16x16x32_bf16(
                        af[mi], bf[ni], acc[mi][ni], 0, 0, 0);
        }

        __builtin_amdgcn_sched_barrier(0);
        __builtin_amdgcn_s_barrier();          // all waves done reading buf
        __builtin_amdgcn_sched_barrier(0);
        if (kt + 2 < NK) GEMM_STAGE(buf, (kt + 2) * 64);
    }
#undef GEMM_STAGE

    float bv[4];
#pragma unroll
    for (int ni = 0; ni < 4; ++ni) bv[ni] = bias[bn + n0w + ni * 16 + l15];

#pragma unroll
    for (int ni = 0; ni < 4; ++ni) {
        const int col   = bn + n0w + ni * 16 + l15;
        const int cm    = col % 192;      // wave-uniform block (no divergence)
        const int vhead = col / 192;
#pragma unroll
        for (int mi = 0; mi < 4; ++mi) {
            const int row0 = bm + m0w + mi * 16 + quad * 4;
            float v[4];
#pragma unroll
            for (int r = 0; r < 4; ++r) v[r] = acc[mi][ni][r] + bv[ni];
            if (OUT_BF16) {
                if (FUSE && cm >= 2 * DHEAD) {
                    // V columns: ONLY the transposed Vt store
                    const int nb = row0 >> 11;       // batch
                    const int s  = row0 & 2047;
                    const int d  = cm - 2 * DHEAD;
                    ushortx4 pk = { f2bf(v[0]), f2bf(v[1]), f2bf(v[2]), f2bf(v[3]) };
                    *(ushortx4*)(Vt + ((size_t)(nb * NHEAD + vhead) * DHEAD + d) * SEQ + s) = pk;
                } else {
                    if (FUSE && cm < DHEAD) {
#pragma unroll
                        for (int r = 0; r < 4; ++r) v[r] *= 0.18033688011112042f;  // log2(e)/8
                    }
                    unsigned short* H = (unsigned short*)Cout;
#pragma unroll
                    for (int r = 0; r < 4; ++r)
                        H[(size_t)(row0 + r) * N + col] = f2bf(v[r]);
                }
            } else {
                float* C = (float*)Cout;
#pragma unroll
                for (int r = 0; r < 4; ++r)
                    C[(size_t)(row0 + r) * N + col] = v[r];
            }
        }
    }
}

// ------------------------- MFMA flash attention v8 --------------------------
// (verbatim round-2/7/10 version: 88-90 us measured; all variants regressed)
// 256 thr = 4 independent waves; wave w owns q rows q0+w*32 .. +31, full d=64.
// Per 16-kv slab: S^T = mfma16x16x32(K,Q) -> exp2 -> pack bf16 in-lane; the
// packed regs ARE the A-fragment of mfma_16x16x16bf16_1k (layout duality), so
// PV needs no LDS P and no cross-lane. Row sums: extra K=16 MFMA vs ones.
// K/V staged in double-buffered LDS; ONE __syncthreads per 64-kv tile.
__global__ __launch_bounds__(256, 4) void attn_mfma(
    const short* __restrict__ h, const short* __restrict__ Vt,
    unsigned short* __restrict__ att)
{
    __shared__ short Ks[2][64 * 64];    // [kv][d], XOR8 16B-chunk swizzle
    __shared__ short Vs[2][64 * 64];    // [d][kv], XOR8 16B-chunk swizzle

    const int t    = threadIdx.x;
    const int lane = t & 63, w = t >> 6;
    const int quad = lane >> 4, l15 = lane & 15;
    const int r7   = l15 & 7;
    const int bh = blockIdx.x, n = bh >> 4, head = bh & 15;
    const int q0 = blockIdx.y * 128 + w * 32;

    const short* hQ  = h + (size_t)n * SEQ * N1 + head * (3 * DHEAD);
    const short* hK  = hQ + DHEAD;
    const short* Vtb = Vt + (size_t)bh * DHEAD * SEQ;

    // staging: thread t owns row t>>2, 16B chunks (t&3)*2 and +1 (K and V)
    const int srow = t >> 2;
    const int sc0  = (t & 3) * 2;
    const int sk   = srow & 7;
    const short* gK = hK  + (size_t)srow * N1  + sc0 * 8;
    const short* gV = Vtb + (size_t)srow * SEQ + sc0 * 8;
    const int oL0 = srow * 64 + ((sc0    ) ^ sk) * 8;
    const int oL1 = srow * 64 + ((sc0 + 1) ^ sk) * 8;

    // Q fragments: 32 rows per wave, hoisted once
    shortx8 qf[2][2];
#pragma unroll
    for (int qt = 0; qt < 2; ++qt)
#pragma unroll
        for (int kt = 0; kt < 2; ++kt)
            qf[qt][kt] = *(const shortx8*)(hQ + (size_t)(q0 + qt * 16 + l15) * N1
                                           + kt * 32 + quad * 8);

    floatx4 O[2][4];                    // q-tile x d-tile, full d per wave
    floatx4 Osum[2];                    // row sums via ones-MFMA
#pragma unroll
    for (int qt = 0; qt < 2; ++qt) {
        Osum[qt] = (floatx4)0.f;
#pragma unroll
        for (int dt = 0; dt < 4; ++dt) O[qt][dt] = (floatx4)0.f;
    }

    const shortx4 ones = { (short)0x3F80, (short)0x3F80, (short)0x3F80, (short)0x3F80 };

    const int NT = SEQ / 64;

    // prologue: tile 0 into buffer 0
    int4 ka = *(const int4*)gK, kb = *(const int4*)(gK + 8);
    int4 va = *(const int4*)gV, vb = *(const int4*)(gV + 8);
    *(int4*)(&Ks[0][oL0]) = ka; *(int4*)(&Ks[0][oL1]) = kb;
    *(int4*)(&Vs[0][oL0]) = va; *(int4*)(&Vs[0][oL1]) = vb;
    gK += (size_t)64 * N1; gV += 64;

    for (int it = 0; it < NT; ++it) {
        const int buf = it & 1;
        __syncthreads();                // buf ready (written prev iter/prologue)

        const bool more = (it + 1 < NT);
        if (more) {                     // issue next-tile global loads early
            ka = *(const int4*)gK; kb = *(const int4*)(gK + 8);
            va = *(const int4*)gV; vb = *(const int4*)(gV + 8);
            gK += (size_t)64 * N1; gV += 64;
        }

        const short* Kb = &Ks[buf][0];
        const short* Vb = &Vs[buf][0];

#pragma unroll
        for (int sl = 0; sl < 4; ++sl) {
            // K fragments (b128, swizzled, 8-lane/chunk = b128 floor)
            const short* krow = Kb + (sl * 16 + l15) * 64;
            shortx8 kf0 = *(const shortx8*)(krow + ((quad ^ r7) * 8));
            shortx8 kf1 = *(const shortx8*)(krow + (((quad ^ 4) ^ r7) * 8));
            // V fragments for K=16 PV: B[k=kv=quad*4+i][col=d=l15] contiguous 8B
            shortx4 vf[4];
#pragma unroll
            for (int dt = 0; dt < 4; ++dt)
                vf[dt] = *(const shortx4*)(Vb + (dt * 16 + l15) * 64
                                           + (((sl * 4 + quad) ^ (r7 << 1)) << 2));

            // S^T then exp2 then pack: registers become PV A-fragments
            shortx4 pa[2];
#pragma unroll
            for (int qt = 0; qt < 2; ++qt) {
                floatx4 s = __builtin_amdgcn_mfma_f32_16x16x32_bf16(
                    kf0, qf[qt][0], (floatx4)0.f, 0, 0, 0);
                s = __builtin_amdgcn_mfma_f32_16x16x32_bf16(
                    kf1, qf[qt][1], s, 0, 0, 0);
                const float p0 = EXP2(s[0]);
                const float p1 = EXP2(s[1]);
                const float p2 = EXP2(s[2]);
                const float p3 = EXP2(s[3]);
                union { uint2 u; shortx4 v; } cv;
                cv.u.x = __builtin_amdgcn_perm(fbits(p1), fbits(p0), 0x07060302u);
                cv.u.y = __builtin_amdgcn_perm(fbits(p3), fbits(p2), 0x07060302u);
                pa[qt] = cv.v;
            }

            // O += P @ V ; Osum += P @ 1 (row sums land in (quad*4+r) layout)
#pragma unroll
            for (int qt = 0; qt < 2; ++qt) {
                Osum[qt] = MFMA_K16(pa[qt], ones, Osum[qt]);
#pragma unroll
                for (int dt = 0; dt < 4; ++dt)
                    O[qt][dt] = MFMA_K16(pa[qt], vf[dt], O[qt][dt]);
            }
        }

        if (more) {                     // stage next tile into other buffer
            short* Kn = &Ks[buf ^ 1][0];
            short* Vn = &Vs[buf ^ 1][0];
            *(int4*)(Kn + oL0) = ka; *(int4*)(Kn + oL1) = kb;
            *(int4*)(Vn + oL0) = va; *(int4*)(Vn + oL1) = vb;
        }
    }

    // epilogue: normalize and store (no cross-lane needed; Osum layout matches)
    const size_t obase = ((size_t)n * SEQ + q0) * E_DIM + head * DHEAD;
#pragma unroll
    for (int qt = 0; qt < 2; ++qt)
#pragma unroll
        for (int r = 0; r < 4; ++r) {
            const float inv = 1.f / Osum[qt][r];
            const size_t row = obase + (size_t)(qt * 16 + quad * 4 + r) * E_DIM;
#pragma unroll
            for (int dt = 0; dt < 4; ++dt)
                att[row + dt * 16 + l15] = f2bf(O[qt][dt][r] * inv);
        }
}

// ------------------------------- launch ------------------------------------
extern "C" void kernel_launch(void* const* d_in, const int* in_sizes, int n_in,
                              void* d_out, int out_size, void* d_ws, size_t ws_size,
                              hipStream_t stream)
{
    const float* x  = (const float*)d_in[0];
    const float* W1 = (const float*)d_in[1];
    const float* b1 = (const float*)d_in[2];
    const float* W2 = (const float*)d_in[3];
    const float* b2 = (const float*)d_in[4];
    float* out = (float*)d_out;

    char* ws = (char*)d_ws;
    unsigned short* x_bf  = (unsigned short*)(ws);                    // 16 MB
    unsigned short* W1t   = (unsigned short*)(ws + (16u << 20));      //  6 MB
    unsigned short* W2t   = (unsigned short*)(ws + (22u << 20));      //  2 MB
    unsigned short* h_bf  = (unsigned short*)(ws + (24u << 20));      // 48 MB
    unsigned short* attb  = (unsigned short*)(ws + (72u << 20));      // 16 MB
    unsigned short* Vtw   = (unsigned short*)(ws + (88u << 20));      // 16 MB

    cvt_bf16<<<dim3((M_TOK * E_DIM) / (256 * 8)), 256, 0, stream>>>(x, x_bf);
    cvt_transpose<<<dim3(N1 / 32, E_DIM / 32), dim3(32, 8), 0, stream>>>(W1, W1t, E_DIM, N1);
    cvt_transpose<<<dim3(E_DIM / 32, E_DIM / 32), dim3(32, 8), 0, stream>>>(W2, W2t, E_DIM, E_DIM);

    // h = x@W1+b1 (bf16; Q cols pre-scaled log2(e)/8; V cols -> Vt only)
    gemm_bf16<true, true><<<dim3(N1 / 128, M_TOK / 128), 256, 0, stream>>>(
        (const short*)x_bf, (const short*)W1t, b1, h_bf, Vtw, M_TOK, N1, E_DIM);

    attn_mfma<<<dim3(NB * NHEAD, SEQ / 128), 256, 0, stream>>>(
        (const short*)h_bf, (const short*)Vtw, attb);

    gemm_bf16<false, false><<<dim3(E_DIM / 128, M_TOK / 128), 256, 0, stream>>>(
        (const short*)attb, (const short*)W2t, b2, out, nullptr, M_TOK, E_DIM, E_DIM);
}

// Round 12
// 265.443 us; speedup vs baseline: 1.1113x; 1.0215x over previous
//
#include <hip/hip_runtime.h>
#include <math.h>
#include <stdint.h>
#include <stddef.h>

// ---------------------------------------------------------------------------
// SelfAttention forward, fp32 I/O, bf16 MFMA internally.
// Round 17: consolidation. XCD swizzle REVERTED (r16 post-mortem: for
// tall-skinny C the default round-robin keeps each XCD's B working set at
// 768 KB (L2-resident); the chunked swizzle forced all 24 B-panels (6 MB)
// through each L2 -> thrash, +7 us). Keep r15's V-column epilogue elision.
// GEMM = round-12-verified 128x128 double-buffered vmcnt(8) pipeline.
// attn = v8 verbatim (88.6 us r11).
// ---------------------------------------------------------------------------

#define SEQ    2048
#define NB     4
#define E_DIM  1024
#define N1     3072
#define M_TOK  8192
#define NHEAD  16
#define DHEAD  64

typedef __attribute__((ext_vector_type(4))) float    floatx4;
typedef __attribute__((ext_vector_type(8))) short    shortx8;
typedef __attribute__((ext_vector_type(4))) short    shortx4;
typedef __attribute__((ext_vector_type(4))) unsigned short ushortx4;

#if __has_builtin(__builtin_amdgcn_exp2f)
#define EXP2(x) __builtin_amdgcn_exp2f(x)
#else
#define EXP2(x) __expf((x) * 0.6931471805599453f)
#endif

// K=16 bf16 MFMA: A,B = 4x bf16 (2 VGPRs), C/D = 4x f32. A layout
// (row=lane&15, k=quad*4+i) is the exact transpose of the 16x16 C/D layout.
#define MFMA_K16(a, b, c) \
    __builtin_amdgcn_mfma_f32_16x16x16bf16_1k((a), (b), (c), 0, 0, 0)

__device__ __forceinline__ unsigned short f2bf(float f) {
    union { float f; unsigned u; } v; v.f = f;
    unsigned r = (v.u + 0x7FFFu + ((v.u >> 16) & 1u)) >> 16;  // RNE
    return (unsigned short)r;
}
__device__ __forceinline__ unsigned fbits(float f) {
    union { float f; unsigned u; } v; v.f = f; return v.u;
}

__device__ __forceinline__ void gl_lds16(const void* g, void* l) {
    __builtin_amdgcn_global_load_lds(
        (const __attribute__((address_space(1))) unsigned int*)g,
        (__attribute__((address_space(3))) unsigned int*)l, 16, 0, 0);
}

// --------------------------- fp32 -> bf16 convert ---------------------------
__global__ __launch_bounds__(256) void cvt_bf16(
    const float* __restrict__ in, unsigned short* __restrict__ out)
{
    const size_t i = ((size_t)blockIdx.x * 256 + threadIdx.x) * 8;
    float4 a = *(const float4*)(in + i);
    float4 b = *(const float4*)(in + i + 4);
    ushortx4 o0 = { f2bf(a.x), f2bf(a.y), f2bf(a.z), f2bf(a.w) };
    ushortx4 o1 = { f2bf(b.x), f2bf(b.y), f2bf(b.z), f2bf(b.w) };
    *(ushortx4*)(out + i)     = o0;
    *(ushortx4*)(out + i + 4) = o1;
}

// -------------------- fp32 [K][N] -> bf16 transposed [N][K] -----------------
__global__ __launch_bounds__(256) void cvt_transpose(
    const float* __restrict__ W, unsigned short* __restrict__ Wt, int K, int N)
{
    __shared__ unsigned short tile[32][33];
    const int tx = threadIdx.x, ty = threadIdx.y;   // (32, 8)
    const int n0 = blockIdx.x * 32, k0 = blockIdx.y * 32;
#pragma unroll
    for (int r = 0; r < 4; ++r) {
        const int k = ty + r * 8;
        tile[tx][k] = f2bf(W[(size_t)(k0 + k) * N + n0 + tx]);
    }
    __syncthreads();
#pragma unroll
    for (int r = 0; r < 4; ++r) {
        const int n = ty + r * 8;
        Wt[(size_t)(n0 + n) * K + k0 + tx] = tile[n][tx];
    }
}

// --------------------------- bf16 MFMA GEMM --------------------------------
// C[M,N] = A[M,K](bf16) @ Bt[N,K](bf16, pre-transposed) + bias[N](f32).
// BM=BN=128, BK=64, DOUBLE-buffered LDS (64 KB, 2 blocks/CU), 2-deep
// prefetch pipeline (vmcnt(8) + raw barriers; no vmcnt(0) drain in-loop).
// XOR8 swizzle via pre-swizzled GLOBAL source chunks + swizzled ds_read.
// Default block->tile mapping (NO XCD swizzle: round-robin already gives
// each XCD a small L2-resident B working set for these tall-skinny shapes).
// FUSE (gemm1): Q cols (col%192<64) pre-scaled by log2(e)/8; V cols
// (col%192>=128) stored ONLY into Vt[bh][d][s] (h_bf V cols never read).
template <bool OUT_BF16, bool FUSE>
__global__ __launch_bounds__(256) void gemm_bf16(
    const short* __restrict__ A, const short* __restrict__ Bt,
    const float* __restrict__ bias, void* __restrict__ Cout,
    unsigned short* __restrict__ Vt,
    int M, int N, int K)
{
    __shared__ short As[2][128 * 64];
    __shared__ short Bs[2][128 * 64];

    const int t    = threadIdx.x;
    const int lane = t & 63, w = t >> 6;
    const int quad = lane >> 4, l15 = lane & 15;
    const int bm = blockIdx.y * 128, bn = blockIdx.x * 128;
    const int m0w = (w >> 1) * 64, n0w = (w & 1) * 64;

    // staging: thread t owns row t>>3 (+32 per round), 16B chunk t&7.
    // Global chunk pre-swizzled by row&7; LDS dest linear (lane*16B per wave).
    const int srow   = t >> 3;            // 0..31
    const int schunk = t & 7;             // 16B chunk in 128B row
    const int gch    = schunk ^ (srow & 7);
    const short* Ag = A  + (size_t)(bm + srow) * K + gch * 8;
    const short* Bg = Bt + (size_t)(bn + srow) * K + gch * 8;
    const int sOff = srow * 64 + schunk * 8;   // shorts

    floatx4 acc[4][4];
#pragma unroll
    for (int i = 0; i < 4; ++i)
#pragma unroll
        for (int j = 0; j < 4; ++j) acc[i][j] = (floatx4)0.f;

    const int NK = K >> 6;     // K/64 K-steps

#define GEMM_STAGE(bufi, k0)                                                   \
    {                                                                          \
        _Pragma("unroll")                                                      \
        for (int r = 0; r < 4; ++r) {                                          \
            gl_lds16(Ag + (size_t)(r * 32) * K + (k0), &As[bufi][sOff + r * 32 * 64]); \
            gl_lds16(Bg + (size_t)(r * 32) * K + (k0), &Bs[bufi][sOff + r * 32 * 64]); \
        }                                                                      \
    }

    // prologue: tiles 0 and 1 in flight (16 outstanding loads)
    GEMM_STAGE(0, 0);
    GEMM_STAGE(1, 64);

    for (int kt = 0; kt < NK; ++kt) {
        const int buf = kt & 1;
        // wait for tile kt (8 newest = tile kt+1 may stay in flight)
        if (kt + 1 < NK) asm volatile("s_waitcnt vmcnt(8)" ::: "memory");
        else             asm volatile("s_waitcnt vmcnt(0)" ::: "memory");
        __builtin_amdgcn_sched_barrier(0);
        __builtin_amdgcn_s_barrier();          // publish tile kt to all waves
        __builtin_amdgcn_sched_barrier(0);

#pragma unroll
        for (int kk = 0; kk < 2; ++kk) {
            shortx8 af[4], bf[4];
#pragma unroll
            for (int mi = 0; mi < 4; ++mi)
                af[mi] = *(const shortx8*)(&As[buf][(m0w + mi * 16 + l15) * 64
                                           + (((kk * 4 + quad) ^ (l15 & 7)) * 8)]);
#pragma unroll
            for (int ni = 0; ni < 4; ++ni)
                bf[ni] = *(const shortx8*)(&Bs[buf][(n0w + ni * 16 + l15) * 64
                                           + (((kk * 4 + quad) ^ (l15 & 7)) * 8)]);
#pragma unroll
            for (int mi = 0; mi < 4; ++mi)
#pragma unroll
                for (int ni = 0; ni < 4; ++ni)
                    acc[mi][ni] = __builtin_amdgcn_mfma_f32_16x16x32_bf16(
                        af[mi], bf[ni], acc[mi][ni], 0, 0, 0);
        }

        __builtin_amdgcn_sched_barrier(0);
        __builtin_amdgcn_s_barrier();          // all waves done reading buf
        __builtin_amdgcn_sched_barrier(0);
        if (kt + 2 < NK) GEMM_STAGE(buf, (kt + 2) * 64);
    }
#undef GEMM_STAGE

    float bv[4];
#pragma unroll
    for (int ni = 0; ni < 4; ++ni) bv[ni] = bias[bn + n0w + ni * 16 + l15];

#pragma unroll
    for (int ni = 0; ni < 4; ++ni) {
        const int col   = bn + n0w + ni * 16 + l15;
        const int cm    = col % 192;      // wave-uniform block (no divergence)
        const int vhead = col / 192;
#pragma unroll
        for (int mi = 0; mi < 4; ++mi) {
            const int row0 = bm + m0w + mi * 16 + quad * 4;
            float v[4];
#pragma unroll
            for (int r = 0; r < 4; ++r) v[r] = acc[mi][ni][r] + bv[ni];
            if (OUT_BF16) {
                if (FUSE && cm >= 2 * DHEAD) {
                    // V columns: ONLY the transposed Vt store
                    const int nb = row0 >> 11;       // batch
                    const int s  = row0 & 2047;
                    const int d  = cm - 2 * DHEAD;
                    ushortx4 pk = { f2bf(v[0]), f2bf(v[1]), f2bf(v[2]), f2bf(v[3]) };
                    *(ushortx4*)(Vt + ((size_t)(nb * NHEAD + vhead) * DHEAD + d) * SEQ + s) = pk;
                } else {
                    if (FUSE && cm < DHEAD) {
#pragma unroll
                        for (int r = 0; r < 4; ++r) v[r] *= 0.18033688011112042f;  // log2(e)/8
                    }
                    unsigned short* H = (unsigned short*)Cout;
#pragma unroll
                    for (int r = 0; r < 4; ++r)
                        H[(size_t)(row0 + r) * N + col] = f2bf(v[r]);
                }
            } else {
                float* C = (float*)Cout;
#pragma unroll
                for (int r = 0; r < 4; ++r)
                    C[(size_t)(row0 + r) * N + col] = v[r];
            }
        }
    }
}

// ------------------------- MFMA flash attention v8 --------------------------
// (verbatim: 88.6-90.4 us measured across r7/r10/r11; all variants regressed)
// 256 thr = 4 independent waves; wave w owns q rows q0+w*32 .. +31, full d=64.
// Per 16-kv slab: S^T = mfma16x16x32(K,Q) -> exp2 -> pack bf16 in-lane; the
// packed regs ARE the A-fragment of mfma_16x16x16bf16_1k (layout duality), so
// PV needs no LDS P and no cross-lane. Row sums: extra K=16 MFMA vs ones.
// K/V staged in double-buffered LDS; ONE __syncthreads per 64-kv tile.
__global__ __launch_bounds__(256, 4) void attn_mfma(
    const short* __restrict__ h, const short* __restrict__ Vt,
    unsigned short* __restrict__ att)
{
    __shared__ short Ks[2][64 * 64];    // [kv][d], XOR8 16B-chunk swizzle
    __shared__ short Vs[2][64 * 64];    // [d][kv], XOR8 16B-chunk swizzle

    const int t    = threadIdx.x;
    const int lane = t & 63, w = t >> 6;
    const int quad = lane >> 4, l15 = lane & 15;
    const int r7   = l15 & 7;
    const int bh = blockIdx.x, n = bh >> 4, head = bh & 15;
    const int q0 = blockIdx.y * 128 + w * 32;

    const short* hQ  = h + (size_t)n * SEQ * N1 + head * (3 * DHEAD);
    const short* hK  = hQ + DHEAD;
    const short* Vtb = Vt + (size_t)bh * DHEAD * SEQ;

    // staging: thread t owns row t>>2, 16B chunks (t&3)*2 and +1 (K and V)
    const int srow = t >> 2;
    const int sc0  = (t & 3) * 2;
    const int sk   = srow & 7;
    const short* gK = hK  + (size_t)srow * N1  + sc0 * 8;
    const short* gV = Vtb + (size_t)srow * SEQ + sc0 * 8;
    const int oL0 = srow * 64 + ((sc0    ) ^ sk) * 8;
    const int oL1 = srow * 64 + ((sc0 + 1) ^ sk) * 8;

    // Q fragments: 32 rows per wave, hoisted once
    shortx8 qf[2][2];
#pragma unroll
    for (int qt = 0; qt < 2; ++qt)
#pragma unroll
        for (int kt = 0; kt < 2; ++kt)
            qf[qt][kt] = *(const shortx8*)(hQ + (size_t)(q0 + qt * 16 + l15) * N1
                                           + kt * 32 + quad * 8);

    floatx4 O[2][4];                    // q-tile x d-tile, full d per wave
    floatx4 Osum[2];                    // row sums via ones-MFMA
#pragma unroll
    for (int qt = 0; qt < 2; ++qt) {
        Osum[qt] = (floatx4)0.f;
#pragma unroll
        for (int dt = 0; dt < 4; ++dt) O[qt][dt] = (floatx4)0.f;
    }

    const shortx4 ones = { (short)0x3F80, (short)0x3F80, (short)0x3F80, (short)0x3F80 };

    const int NT = SEQ / 64;

    // prologue: tile 0 into buffer 0
    int4 ka = *(const int4*)gK, kb = *(const int4*)(gK + 8);
    int4 va = *(const int4*)gV, vb = *(const int4*)(gV + 8);
    *(int4*)(&Ks[0][oL0]) = ka; *(int4*)(&Ks[0][oL1]) = kb;
    *(int4*)(&Vs[0][oL0]) = va; *(int4*)(&Vs[0][oL1]) = vb;
    gK += (size_t)64 * N1; gV += 64;

    for (int it = 0; it < NT; ++it) {
        const int buf = it & 1;
        __syncthreads();                // buf ready (written prev iter/prologue)

        const bool more = (it + 1 < NT);
        if (more) {                     // issue next-tile global loads early
            ka = *(const int4*)gK; kb = *(const int4*)(gK + 8);
            va = *(const int4*)gV; vb = *(const int4*)(gV + 8);
            gK += (size_t)64 * N1; gV += 64;
        }

        const short* Kb = &Ks[buf][0];
        const short* Vb = &Vs[buf][0];

#pragma unroll
        for (int sl = 0; sl < 4; ++sl) {
            // K fragments (b128, swizzled, 8-lane/chunk = b128 floor)
            const short* krow = Kb + (sl * 16 + l15) * 64;
            shortx8 kf0 = *(const shortx8*)(krow + ((quad ^ r7) * 8));
            shortx8 kf1 = *(const shortx8*)(krow + (((quad ^ 4) ^ r7) * 8));
            // V fragments for K=16 PV: B[k=kv=quad*4+i][col=d=l15] contiguous 8B
            shortx4 vf[4];
#pragma unroll
            for (int dt = 0; dt < 4; ++dt)
                vf[dt] = *(const shortx4*)(Vb + (dt * 16 + l15) * 64
                                           + (((sl * 4 + quad) ^ (r7 << 1)) << 2));

            // S^T then exp2 then pack: registers become PV A-fragments
            shortx4 pa[2];
#pragma unroll
            for (int qt = 0; qt < 2; ++qt) {
                floatx4 s = __builtin_amdgcn_mfma_f32_16x16x32_bf16(
                    kf0, qf[qt][0], (floatx4)0.f, 0, 0, 0);
                s = __builtin_amdgcn_mfma_f32_16x16x32_bf16(
                    kf1, qf[qt][1], s, 0, 0, 0);
                const float p0 = EXP2(s[0]);
                const float p1 = EXP2(s[1]);
                const float p2 = EXP2(s[2]);
                const float p3 = EXP2(s[3]);
                union { uint2 u; shortx4 v; } cv;
                cv.u.x = __builtin_amdgcn_perm(fbits(p1), fbits(p0), 0x07060302u);
                cv.u.y = __builtin_amdgcn_perm(fbits(p3), fbits(p2), 0x07060302u);
                pa[qt] = cv.v;
            }

            // O += P @ V ; Osum += P @ 1 (row sums land in (quad*4+r) layout)
#pragma unroll
            for (int qt = 0; qt < 2; ++qt) {
                Osum[qt] = MFMA_K16(pa[qt], ones, Osum[qt]);
#pragma unroll
                for (int dt = 0; dt < 4; ++dt)
                    O[qt][dt] = MFMA_K16(pa[qt], vf[dt], O[qt][dt]);
            }
        }

        if (more) {                     // stage next tile into other buffer
            short* Kn = &Ks[buf ^ 1][0];
            short* Vn = &Vs[buf ^ 1][0];
            *(int4*)(Kn + oL0) = ka; *(int4*)(Kn + oL1) = kb;
            *(int4*)(Vn + oL0) = va; *(int4*)(Vn + oL1) = vb;
        }
    }

    // epilogue: normalize and store (no cross-lane needed; Osum layout matches)
    const size_t obase = ((size_t)n * SEQ + q0) * E_DIM + head * DHEAD;
#pragma unroll
    for (int qt = 0; qt < 2; ++qt)
#pragma unroll
        for (int r = 0; r < 4; ++r) {
            const float inv = 1.f / Osum[qt][r];
            const size_t row = obase + (size_t)(qt * 16 + quad * 4 + r) * E_DIM;
#pragma unroll
            for (int dt = 0; dt < 4; ++dt)
                att[row + dt * 16 + l15] = f2bf(O[qt][dt][r] * inv);
        }
}

// ------------------------------- launch ------------------------------------
extern "C" void kernel_launch(void* const* d_in, const int* in_sizes, int n_in,
                              void* d_out, int out_size, void* d_ws, size_t ws_size,
                              hipStream_t stream)
{
    const float* x  = (const float*)d_in[0];
    const float* W1 = (const float*)d_in[1];
    const float* b1 = (const float*)d_in[2];
    const float* W2 = (const float*)d_in[3];
    const float* b2 = (const float*)d_in[4];
    float* out = (float*)d_out;

    char* ws = (char*)d_ws;
    unsigned short* x_bf  = (unsigned short*)(ws);                    // 16 MB
    unsigned short* W1t   = (unsigned short*)(ws + (16u << 20));      //  6 MB
    unsigned short* W2t   = (unsigned short*)(ws + (22u << 20));      //  2 MB
    unsigned short* h_bf  = (unsigned short*)(ws + (24u << 20));      // 48 MB
    unsigned short* attb  = (unsigned short*)(ws + (72u << 20));      // 16 MB
    unsigned short* Vtw   = (unsigned short*)(ws + (88u << 20));      // 16 MB

    cvt_bf16<<<dim3((M_TOK * E_DIM) / (256 * 8)), 256, 0, stream>>>(x, x_bf);
    cvt_transpose<<<dim3(N1 / 32, E_DIM / 32), dim3(32, 8), 0, stream>>>(W1, W1t, E_DIM, N1);
    cvt_transpose<<<dim3(E_DIM / 32, E_DIM / 32), dim3(32, 8), 0, stream>>>(W2, W2t, E_DIM, E_DIM);

    // h = x@W1+b1 (bf16; Q cols pre-scaled log2(e)/8; V cols -> Vt only)
    gemm_bf16<true, true><<<dim3(N1 / 128, M_TOK / 128), 256, 0, stream>>>(
        (const short*)x_bf, (const short*)W1t, b1, h_bf, Vtw, M_TOK, N1, E_DIM);

    attn_mfma<<<dim3(NB * NHEAD, SEQ / 128), 256, 0, stream>>>(
        (const short*)h_bf, (const short*)Vtw, attb);

    gemm_bf16<false, false><<<dim3(E_DIM / 128, M_TOK / 128), 256, 0, stream>>>(
        (const short*)attb, (const short*)W2t, b2, out, nullptr, M_TOK, E_DIM, E_DIM);
}